// Round 2
// baseline (345.999 us; speedup 1.0000x reference)
//
#include <hip/hip_runtime.h>

#define N_ELEM 262144   // 1*512*512 per batch image
#define NT 1024         // threads per top-k block
#define CAP 2048        // LDS candidate buffer entries
#define TIE_CAP 512
#define NCOPY 16        // histogram replication (LDS banks)

// Order-preserving float->uint key: larger float => larger key.
__device__ __forceinline__ unsigned keyOf(float f) {
    unsigned u = __float_as_uint(f);
    return (u & 0x80000000u) ? ~u : (u | 0x80000000u);
}

// One block per (batch, tensor). t=0: rv (K=180), t=1: ri (K=180), t=2: rf (K=360).
// Writes K indices (unordered set, exact top-k with lowest-index tie break)
// to idx_out + blockIdx.x*360.
// LDS budget: 16K (hist1) + 1K (hist2) + 16K (cand) + 2K (ties) ~= 36 KB < 64 KB.
__global__ __launch_bounds__(NT) void topk_kernel(const float* __restrict__ rv,
                                                  const float* __restrict__ ri,
                                                  const float* __restrict__ rf,
                                                  int* __restrict__ idx_out) {
    const int t = blockIdx.x % 3;
    const int b = blockIdx.x / 3;
    const float* src = (t == 0 ? rv : (t == 1 ? ri : rf)) + (size_t)b * N_ELEM;
    const int K = (t == 2) ? 360 : 180;
    int* obuf = idx_out + (size_t)blockIdx.x * 360;

    __shared__ unsigned hist1[256 * NCOPY];   // 16 KB, [bin*NCOPY + copy]
    __shared__ unsigned hist2[256];           // 1 KB
    __shared__ unsigned candKey[CAP];         // 8 KB
    __shared__ int      candIdx[CAP];         // 8 KB
    __shared__ int ties[TIE_CAP];             // 2 KB
    __shared__ unsigned s_prefix; __shared__ int s_bits;
    __shared__ int s_cntgt; __shared__ int s_bincnt;
    __shared__ int s_cn; __shared__ int s_on; __shared__ int s_tn;
    __shared__ unsigned s_p2; __shared__ int s_b2; __shared__ int s_cg2;

    const int tid = threadIdx.x;
    const int copy = tid & (NCOPY - 1);

    for (int i = tid; i < 256 * NCOPY; i += NT) hist1[i] = 0;
    __syncthreads();

    // ---- Phase 1: 8-bit MSB histogram over all elements ----
    const float4* p4 = (const float4*)src;
    for (int i = tid; i < N_ELEM / 4; i += NT) {
        float4 v = p4[i];
        atomicAdd(&hist1[(keyOf(v.x) >> 24) * NCOPY + copy], 1u);
        atomicAdd(&hist1[(keyOf(v.y) >> 24) * NCOPY + copy], 1u);
        atomicAdd(&hist1[(keyOf(v.z) >> 24) * NCOPY + copy], 1u);
        atomicAdd(&hist1[(keyOf(v.w) >> 24) * NCOPY + copy], 1u);
    }
    __syncthreads();
    if (tid < 256) {                 // reduce NCOPY copies -> hist2[0..255]
        unsigned s = 0;
        for (int c = 0; c < NCOPY; ++c) s += hist1[tid * NCOPY + c];
        hist2[tid] = s;
    }
    __syncthreads();
    if (tid == 0) {                  // suffix scan from top to find k-th bin
        int cum = 0; int bin = 255;
        for (; bin >= 0; --bin) {
            int c = (int)hist2[bin];
            if (cum + c >= K) break;
            cum += c;
        }
        s_prefix = (unsigned)bin; s_bits = 8;
        s_cntgt = cum; s_bincnt = (int)hist2[bin];
    }

    // ---- Refine prefix (8 bits per pass over global data) until the selected
    //      bin is small enough that all candidates fit in CAP. ----
    while (true) {
        __syncthreads();
        if (s_bincnt <= CAP - 512 || s_bits >= 32) break;
        for (int i = tid; i < 256; i += NT) hist2[i] = 0;
        __syncthreads();
        {
            int sh = 32 - s_bits; unsigned pref = s_prefix;
            int sh2 = sh - 8;
            for (int i = tid; i < N_ELEM / 4; i += NT) {
                float4 v = p4[i];
                unsigned kk;
                kk = keyOf(v.x); if ((kk >> sh) == pref) atomicAdd(&hist2[(kk >> sh2) & 255u], 1u);
                kk = keyOf(v.y); if ((kk >> sh) == pref) atomicAdd(&hist2[(kk >> sh2) & 255u], 1u);
                kk = keyOf(v.z); if ((kk >> sh) == pref) atomicAdd(&hist2[(kk >> sh2) & 255u], 1u);
                kk = keyOf(v.w); if ((kk >> sh) == pref) atomicAdd(&hist2[(kk >> sh2) & 255u], 1u);
            }
        }
        __syncthreads();
        if (tid == 0) {
            int r = K - s_cntgt; int cum = 0; int d = 255;
            for (; d >= 0; --d) {
                int c = (int)hist2[d];
                if (cum + c >= r) break;
                cum += c;
            }
            s_cntgt += cum;
            s_prefix = (s_prefix << 8) | (unsigned)d;
            s_bits += 8;
            s_bincnt = (int)hist2[d];
        }
    }
    __syncthreads();
    if (tid == 0) s_cn = 0;
    __syncthreads();

    // ---- Phase 2: collect all candidates with key-prefix >= selected bin ----
    {
        int sh = 32 - s_bits; unsigned pref = s_prefix;
        for (int i = tid; i < N_ELEM / 4; i += NT) {
            float4 v = p4[i];
            unsigned kk; int p;
            kk = keyOf(v.x); if ((kk >> sh) >= pref) { p = atomicAdd(&s_cn, 1); if (p < CAP) { candKey[p] = kk; candIdx[p] = 4 * i + 0; } }
            kk = keyOf(v.y); if ((kk >> sh) >= pref) { p = atomicAdd(&s_cn, 1); if (p < CAP) { candKey[p] = kk; candIdx[p] = 4 * i + 1; } }
            kk = keyOf(v.z); if ((kk >> sh) >= pref) { p = atomicAdd(&s_cn, 1); if (p < CAP) { candKey[p] = kk; candIdx[p] = 4 * i + 2; } }
            kk = keyOf(v.w); if ((kk >> sh) >= pref) { p = atomicAdd(&s_cn, 1); if (p < CAP) { candKey[p] = kk; candIdx[p] = 4 * i + 3; } }
        }
    }
    __syncthreads();
    int cn = s_cn; if (cn > CAP) cn = CAP;

    // ---- Phase 3: exact 32-bit radix select (rank K) among candidates, in LDS ----
    if (tid == 0) { s_p2 = 0; s_b2 = 0; s_cg2 = 0; }
    while (true) {
        __syncthreads();
        if (s_b2 >= 32) break;
        for (int i = tid; i < 256; i += NT) hist2[i] = 0;
        __syncthreads();
        {
            int b2 = s_b2; unsigned p2 = s_p2;
            int sh2 = 32 - b2 - 8;
            for (int i = tid; i < cn; i += NT) {
                unsigned kk = candKey[i];
                bool match = (b2 == 0) || ((kk >> (32 - b2)) == p2);
                if (match) atomicAdd(&hist2[(kk >> sh2) & 255u], 1u);
            }
        }
        __syncthreads();
        if (tid == 0) {
            int r = K - s_cg2; int cum = 0; int d = 255;
            for (; d >= 0; --d) {
                int c = (int)hist2[d];
                if (cum + c >= r) break;
                cum += c;
            }
            s_cg2 += cum;
            s_p2 = (s_p2 << 8) | (unsigned)d;
            s_b2 += 8;
        }
    }
    __syncthreads();
    if (tid == 0) { s_on = 0; s_tn = 0; }
    __syncthreads();

    // ---- Phase 4: emit indices; ties at the k-th value take lowest indices ----
    {
        unsigned Kth = s_p2;
        for (int i = tid; i < cn; i += NT) {
            unsigned kk = candKey[i];
            int idx = candIdx[i];
            if (kk > Kth) { int p = atomicAdd(&s_on, 1); obuf[p] = idx; }
            else if (kk == Kth) { int p = atomicAdd(&s_tn, 1); if (p < TIE_CAP) ties[p] = idx; }
        }
    }
    __syncthreads();
    if (tid == 0) {
        int need = K - s_cg2;                       // tie slots to fill (>=1)
        int tn = s_tn; if (tn > TIE_CAP) tn = TIE_CAP;
        int rr = need; if (rr > tn) rr = tn;        // safety clamp (degenerate only)
        for (int a = 0; a < rr; ++a) {              // selection sort: rr smallest indices
            int mb = a;
            for (int j = a + 1; j < tn; ++j) if (ties[j] < ties[mb]) mb = j;
            int tmp = ties[a]; ties[a] = ties[mb]; ties[mb] = tmp;
            obuf[s_on + a] = ties[a];
        }
        for (int a = rr; a < need; ++a) obuf[s_on + a] = (tn > 0) ? ties[0] : 0; // degenerate fill
    }
}

// One block per batch: union(rv,ri) dedupe + Chebyshev<=3 coverage vs rf set.
__global__ __launch_bounds__(256) void coverage_kernel(const int* __restrict__ idx_buf,
                                                       float* __restrict__ out,
                                                       float inv_b) {
    const int b = blockIdx.x;
    __shared__ int cnd[360];
    __shared__ int fy[360];
    __shared__ int fx[360];
    __shared__ int s_u, s_c;
    const int* rvI = idx_buf + (size_t)(b * 3 + 0) * 360;
    const int* riI = idx_buf + (size_t)(b * 3 + 1) * 360;
    const int* rfI = idx_buf + (size_t)(b * 3 + 2) * 360;
    const int tid = threadIdx.x;

    for (int i = tid; i < 180; i += blockDim.x) { cnd[i] = rvI[i]; cnd[180 + i] = riI[i]; }
    for (int i = tid; i < 360; i += blockDim.x) { int v = rfI[i]; fy[i] = v >> 9; fx[i] = v & 511; }
    if (tid == 0) { s_u = 0; s_c = 0; }
    __syncthreads();

    for (int i = tid; i < 360; i += blockDim.x) {
        int v = cnd[i];
        bool dup = false;
        for (int j = 0; j < i; ++j) if (cnd[j] == v) { dup = true; break; }
        if (!dup) {
            atomicAdd(&s_u, 1);
            int y = v >> 9, x = v & 511;
            bool cov = false;
            for (int j = 0; j < 360; ++j) {
                int dy = y - fy[j]; if (dy < 0) dy = -dy;
                int dx = x - fx[j]; if (dx < 0) dx = -dx;
                if (dy <= 3 && dx <= 3) { cov = true; break; }
            }
            if (cov) atomicAdd(&s_c, 1);
        }
    }
    __syncthreads();
    if (tid == 0) {
        float denom = (float)(s_u > 0 ? s_u : 1);
        float loss = 1.0f - (float)s_c / denom;
        atomicAdd(out, loss * inv_b);
    }
}

extern "C" void kernel_launch(void* const* d_in, const int* in_sizes, int n_in,
                              void* d_out, int out_size, void* d_ws, size_t ws_size,
                              hipStream_t stream) {
    const float* rv = (const float*)d_in[0];
    const float* ri = (const float*)d_in[1];
    const float* rf = (const float*)d_in[2];
    float* out = (float*)d_out;
    int* idx_buf = (int*)d_ws;                 // needs B*3*360*4 bytes (135 KB for B=32)

    const int B = in_sizes[0] / N_ELEM;

    hipMemsetAsync(d_out, 0, sizeof(float), stream);
    topk_kernel<<<B * 3, NT, 0, stream>>>(rv, ri, rf, idx_buf);
    coverage_kernel<<<B, 256, 0, stream>>>(idx_buf, out, 1.0f / (float)B);
}